// Round 7
// baseline (320.894 us; speedup 1.0000x reference)
//
#include <hip/hip_runtime.h>

// Problem constants (B,C,H,W)=(32,64,64,64), code_size=512
#define HWDIM 4096
#define CDIM  64
#define KDIM  512
#define ST_ELEMS   8388608   // 32*64*64*64
#define LOSS_OFF   8519680   // ST_ELEMS + 32*64*64

#define REP64(M) M(0) M(1) M(2) M(3) M(4) M(5) M(6) M(7) M(8) M(9) \
  M(10) M(11) M(12) M(13) M(14) M(15) M(16) M(17) M(18) M(19) \
  M(20) M(21) M(22) M(23) M(24) M(25) M(26) M(27) M(28) M(29) \
  M(30) M(31) M(32) M(33) M(34) M(35) M(36) M(37) M(38) M(39) \
  M(40) M(41) M(42) M(43) M(44) M(45) M(46) M(47) M(48) M(49) \
  M(50) M(51) M(52) M(53) M(54) M(55) M(56) M(57) M(58) M(59) \
  M(60) M(61) M(62) M(63)

// 16-float row chunks (kept from R6 — neutral-to-positive).
typedef float vf16 __attribute__((ext_vector_type(16)));
typedef __attribute__((address_space(4))) const vf16 cvf16;

// numpy fp32 pairwise sum-of-squares (AVX-512 npyv emulation) — array form,
// used for codebook rows. Bit-validated R1-R6.
__device__ __forceinline__ float np_sumsq64(const float a[64]) {
#pragma clang fp contract(off)
  float v[16];
#pragma unroll
  for (int i = 0; i < 16; ++i) {
    float s0 = a[i]      * a[i];
    float s1 = a[i + 16] * a[i + 16];
    float s2 = a[i + 32] * a[i + 32];
    float s3 = a[i + 48] * a[i + 48];
    v[i] = (s0 + s1) + (s2 + s3);
  }
  float t0 = (v[0] + v[8])  + (v[4] + v[12]);
  float t1 = (v[1] + v[9])  + (v[5] + v[13]);
  float t2 = (v[2] + v[10]) + (v[6] + v[14]);
  float t3 = (v[3] + v[11]) + (v[7] + v[15]);
  return (t0 + t2) + (t1 + t3);
}

// Named-register numpy sum-of-squares tree for pinned per-pixel registers.
#define SUMSQ16(P, V, I, J, K, L) \
  float V = ((P##I * P##I) + (P##J * P##J)) + ((P##K * P##K) + (P##L * P##L));
#define SUMSQ_NAMED(P, OUT) { \
  _Pragma("clang fp contract(off)") \
  SUMSQ16(P, q0, 0,16,32,48)  SUMSQ16(P, q1, 1,17,33,49) \
  SUMSQ16(P, q2, 2,18,34,50)  SUMSQ16(P, q3, 3,19,35,51) \
  SUMSQ16(P, q4, 4,20,36,52)  SUMSQ16(P, q5, 5,21,37,53) \
  SUMSQ16(P, q6, 6,22,38,54)  SUMSQ16(P, q7, 7,23,39,55) \
  SUMSQ16(P, q8, 8,24,40,56)  SUMSQ16(P, q9, 9,25,41,57) \
  SUMSQ16(P, q10,10,26,42,58) SUMSQ16(P, q11,11,27,43,59) \
  SUMSQ16(P, q12,12,28,44,60) SUMSQ16(P, q13,13,29,45,61) \
  SUMSQ16(P, q14,14,30,46,62) SUMSQ16(P, q15,15,31,47,63) \
  float t0 = (q0 + q8)  + (q4 + q12); \
  float t1 = (q1 + q9)  + (q5 + q13); \
  float t2 = (q2 + q10) + (q6 + q14); \
  float t3 = (q3 + q11) + (q7 + q15); \
  OUT = (t0 + t2) + (t1 + t3); }

// 2 pixels/thread: 256 blocks x 256 threads = 1 block/CU = 1 wave/SIMD.
// waves_per_eu(1,1): unlock the full VGPR budget (128 pinned x-regs + 8 acc
// + chunk staging ~ 210 VGPRs); occupancy is grid-limited to 1 wave/EU anyway.
// Rationale (R1-R6): three row-delivery paths (VMEM broadcast, LDS, const-AS)
// all plateau ~192-212us -> bound by ~8-12cyc per 16B row chunk delivered.
// 2px doubles FMAs per chunk (64->128 per 4-row CHUNK) -> VALU-bound.
__global__ __launch_bounds__(256)
__attribute__((amdgpu_waves_per_eu(1, 1)))
void vq_kernel(
    const float* __restrict__ x, const float* __restrict__ cb,
    float* __restrict__ st, float* __restrict__ idxo, float* __restrict__ loss)
{
  __shared__ float sc[KDIM];
  __shared__ float lred[4];

  const int tid = threadIdx.x;
  const int b   = blockIdx.x & 31;           // batch index
  const int seg = blockIdx.x >> 5;           // 0..7: 512-pixel segment
  const int p0  = (seg << 9) + tid;          // pixel A
  const int p1  = p0 + 256;                  // pixel B

  cvf16* rows = (cvf16*)(uintptr_t)cb;       // row k = chunks [4k..4k+3]

  // Per-block codebook sum-of-squares (identical fp32 bits in every block).
  for (int k = tid; k < KDIM; k += 256) {
    float row[64];
#pragma unroll
    for (int c = 0; c < 64; ++c) row[c] = cb[(k << 6) + c];
    sc[k] = np_sumsq64(row);
  }

  // Load both pixels into named, pinned registers (coalesced: lane = p).
  const float* xp = x + (size_t)b * (CDIM * HWDIM) + p0;
  const float* yp = x + (size_t)b * (CDIM * HWDIM) + p1;
#define XLOAD(i) float x##i = xp[(i) * HWDIM]; asm("" : "+v"(x##i));
  REP64(XLOAD)
#undef XLOAD
#define YLOAD(i) float y##i = yp[(i) * HWDIM]; asm("" : "+v"(y##i));
  REP64(YLOAD)
#undef YLOAD

  float Sx, Sy;
  SUMSQ_NAMED(x, Sx)
  SUMSQ_NAMED(y, Sy)
  __syncthreads();

  // Argmin over 512 codes, 4 rows/group, both pixels per chunk.
  // Per-(px,row) chain: sequential fused-FMA ascending c — bit-identical to
  // R1-R6; (S - 2*dot) + sc[k]; ascending-k strict '<'.
  float bestd0 = __builtin_inff(), bestd1 = __builtin_inff();
  int   besti0 = 0, besti1 = 0;

#define FF(T, XI) \
    d00 = __builtin_fmaf(x##XI, c0[T], d00); \
    d01 = __builtin_fmaf(y##XI, c0[T], d01); \
    d10 = __builtin_fmaf(x##XI, c1[T], d10); \
    d11 = __builtin_fmaf(y##XI, c1[T], d11); \
    d20 = __builtin_fmaf(x##XI, c2[T], d20); \
    d21 = __builtin_fmaf(y##XI, c2[T], d21); \
    d30 = __builtin_fmaf(x##XI, c3[T], d30); \
    d31 = __builtin_fmaf(y##XI, c3[T], d31);
#define CHUNK(J, A0,A1,A2,A3,A4,A5,A6,A7,A8,A9,A10,A11,A12,A13,A14,A15) \
  { vf16 c0 = rows[rb + (J)];      vf16 c1 = rows[rb + 4 + (J)];        \
    vf16 c2 = rows[rb + 8 + (J)];  vf16 c3 = rows[rb + 12 + (J)];       \
    FF(0,A0) FF(1,A1) FF(2,A2) FF(3,A3) FF(4,A4) FF(5,A5) FF(6,A6)      \
    FF(7,A7) FF(8,A8) FF(9,A9) FF(10,A10) FF(11,A11) FF(12,A12)         \
    FF(13,A13) FF(14,A14) FF(15,A15) }

  for (int k = 0; k < KDIM; k += 4) {
    const int rb = k << 2;
    float d00 = 0.f, d01 = 0.f, d10 = 0.f, d11 = 0.f;
    float d20 = 0.f, d21 = 0.f, d30 = 0.f, d31 = 0.f;
    CHUNK(0,  0, 1, 2, 3, 4, 5, 6, 7, 8, 9,10,11,12,13,14,15)
    CHUNK(1, 16,17,18,19,20,21,22,23,24,25,26,27,28,29,30,31)
    CHUNK(2, 32,33,34,35,36,37,38,39,40,41,42,43,44,45,46,47)
    CHUNK(3, 48,49,50,51,52,53,54,55,56,57,58,59,60,61,62,63)
    float e00, e01, e10, e11, e20, e21, e30, e31;
    {
#pragma clang fp contract(off)
      e00 = (Sx - (d00 + d00)) + sc[k];
      e01 = (Sy - (d01 + d01)) + sc[k];
      e10 = (Sx - (d10 + d10)) + sc[k + 1];
      e11 = (Sy - (d11 + d11)) + sc[k + 1];
      e20 = (Sx - (d20 + d20)) + sc[k + 2];
      e21 = (Sy - (d21 + d21)) + sc[k + 2];
      e30 = (Sx - (d30 + d30)) + sc[k + 3];
      e31 = (Sy - (d31 + d31)) + sc[k + 3];
    }
    if (e00 < bestd0) { bestd0 = e00; besti0 = k; }
    if (e10 < bestd0) { bestd0 = e10; besti0 = k + 1; }
    if (e20 < bestd0) { bestd0 = e20; besti0 = k + 2; }
    if (e30 < bestd0) { bestd0 = e30; besti0 = k + 3; }
    if (e01 < bestd1) { bestd1 = e01; besti1 = k; }
    if (e11 < bestd1) { bestd1 = e11; besti1 = k + 1; }
    if (e21 < bestd1) { bestd1 = e21; besti1 = k + 2; }
    if (e31 < bestd1) { bestd1 = e31; besti1 = k + 3; }
  }
#undef CHUNK
#undef FF

  // Epilogue for both pixels: gather chosen rows (divergent, contiguous 256B
  // per lane), write st (coalesced), accumulate loss partials.
  const float* crow0 = cb + (besti0 << 6);
  const float* crow1 = cb + (besti1 << 6);
  float* stp0 = st + (size_t)b * (CDIM * HWDIM) + p0;
  float* stp1 = st + (size_t)b * (CDIM * HWDIM) + p1;
  float lsum = 0.f;
#define EPI(i) { float cv = crow0[i]; float df; \
    { _Pragma("clang fp contract(off)") df = cv - x##i; } \
    lsum = __builtin_fmaf(df, df, lsum); stp0[(i) * HWDIM] = cv; }
  REP64(EPI)
#undef EPI
#define EPI(i) { float cv = crow1[i]; float df; \
    { _Pragma("clang fp contract(off)") df = cv - y##i; } \
    lsum = __builtin_fmaf(df, df, lsum); stp1[(i) * HWDIM] = cv; }
  REP64(EPI)
#undef EPI

  // indices[b, p] as float (d_out is one flat float32 buffer).
  idxo[b * HWDIM + p0] = (float)besti0;
  idxo[b * HWDIM + p1] = (float)besti1;

  // Block reduce loss, one atomic per block. 1.25/(N*C) is exact pow2*5.
#pragma unroll
  for (int off = 32; off > 0; off >>= 1) lsum += __shfl_down(lsum, off);
  if ((tid & 63) == 0) lred[tid >> 6] = lsum;
  __syncthreads();
  if (tid == 0) {
    float t = (lred[0] + lred[1]) + (lred[2] + lred[3]);
    atomicAdd(loss, t * (1.25f / 8388608.f));
  }
}

extern "C" void kernel_launch(void* const* d_in, const int* in_sizes, int n_in,
                              void* d_out, int out_size, void* d_ws, size_t ws_size,
                              hipStream_t stream) {
  const float* x  = (const float*)d_in[0];   // (32,64,64,64) fp32
  const float* cb = (const float*)d_in[1];   // (512,64) fp32
  float* st   = (float*)d_out;               // (32,64,64,64)
  float* idxo = (float*)d_out + ST_ELEMS;    // (32,64,64) as float
  float* loss = (float*)d_out + LOSS_OFF;    // scalar

  hipMemsetAsync(loss, 0, sizeof(float), stream);  // d_out is poisoned each call
  vq_kernel<<<dim3(256), dim3(256), 0, stream>>>(x, cb, st, idxo, loss);
}